// Round 12
// baseline (350.352 us; speedup 1.0000x reference)
//
#include <hip/hip_runtime.h>

// Scaled dot-product attention, B=4 H=16 S=2048 D=64, fp32 in/out.
// R18 = R17 resubmitted (R17 bench: "MI355X container failed twice" --
// same transient-infra signature as R10; audit found no hang path) with
// two hardenings: (a) variable `half` renamed `kvh` (avoids shadowing a
// HIP type), (b) combine visibility upgraded to the standard pattern:
// ALL threads __threadfence() -> syncthreads -> tid0 atomicAdd (R17 had
// only tid0 fencing, which formally doesn't order other threads' partial
// stores; now independent of the undefined block->XCD mapping).
// R17 theory: split-K x2 -- scheduling is exhausted (R11/13/15/16 all
// 87-92us; 30% no-issue cycles from 2 waves/SIMD TLP). Two blocks per
// (bh,qblk) over key halves -> 1024 blocks = 4 blocks/CU = 4 waves/SIMD,
// keeping 64q/wave LDS amortization. No running max (raw exp2) so
// partials combine additively: out = (o0+o1)/(lac0+lac1), last finisher
// combines. ws guard: needs 101.7MB else nhalf=1 (= R12 exactly).

#define S_LEN 2048
#define D_DIM 64
#define N_BH  64
#define QSCALE 0.18033688011112042f  // (1/sqrt(64)) * log2(e)

typedef _Float16 half8 __attribute__((ext_vector_type(8)));
typedef _Float16 half4 __attribute__((ext_vector_type(4)));
typedef float floatx16 __attribute__((ext_vector_type(16)));
typedef unsigned int uint4v __attribute__((ext_vector_type(4)));

#define MFMA32(a, b, c) __builtin_amdgcn_mfma_f32_32x32x16_f16((a), (b), (c), 0, 0, 0)

#define GLL16(g, l) __builtin_amdgcn_global_load_lds(                      \
    (const __attribute__((address_space(1))) void*)(g),                    \
    (__attribute__((address_space(3))) void*)(l), 16, 0, 0)

// ---- pre-pass: K fp32 -> f16 (same layout, streaming); V fp32 -> f16
// transposed to [bh][d][s'] where s' = s with bits 2<->3 swapped.
// Also zeroes the split-K combine flags (visible to fa via kernel order).
__global__ __launch_bounds__(256) void prep_kernel(
    const float* __restrict__ kg, const float* __restrict__ vg,
    _Float16* __restrict__ kh, _Float16* __restrict__ vt,
    int* __restrict__ flags, int nhalf)
{
    __shared__ _Float16 Ls[64 * 132];
    const int tid = threadIdx.x;
    const int bh = blockIdx.y;
    const int sbase = blockIdx.x * 128;
    const size_t gbase = ((size_t)(bh * S_LEN + sbase)) * D_DIM;  // 8192 floats

    if (nhalf == 2 && blockIdx.x == 0 && tid < 8) flags[(bh << 3) | tid] = 0;

#pragma unroll
    for (int i = 0; i < 8; ++i) {
        const int e = i * 1024 + tid * 4;
        const float4 kv = *(const float4*)(kg + gbase + e);
        half4 hk;
        hk[0] = (_Float16)kv.x; hk[1] = (_Float16)kv.y;
        hk[2] = (_Float16)kv.z; hk[3] = (_Float16)kv.w;
        *(half4*)(kh + gbase + e) = hk;
    }
#pragma unroll
    for (int i = 0; i < 8; ++i) {
        const int e = i * 1024 + tid * 4;
        const int s = e >> 6, d0 = e & 63;
        const float4 vv = *(const float4*)(vg + gbase + e);
        const int sp = (s & ~12) | ((s & 4) << 1) | ((s & 8) >> 1);  // b2<->b3
        Ls[(d0 + 0) * 132 + sp] = (_Float16)vv.x;
        Ls[(d0 + 1) * 132 + sp] = (_Float16)vv.y;
        Ls[(d0 + 2) * 132 + sp] = (_Float16)vv.z;
        Ls[(d0 + 3) * 132 + sp] = (_Float16)vv.w;
    }
    __syncthreads();
    const int w = tid >> 6, L = tid & 63;
    const int dr = L >> 4;
    const int c  = L & 15;
#pragma unroll
    for (int k = 0; k < 4; ++k) {
        const int d = w * 16 + k * 4 + dr;
        const half4 lo = *(const half4*)&Ls[d * 132 + c * 8];
        const half4 hi = *(const half4*)&Ls[d * 132 + c * 8 + 4];
        half8 o;
        o[0] = lo[0]; o[1] = lo[1]; o[2] = lo[2]; o[3] = lo[3];
        o[4] = hi[0]; o[5] = hi[1]; o[6] = hi[2]; o[7] = hi[3];
        *(half8*)(vt + ((size_t)(bh * D_DIM + d)) * S_LEN + sbase + c * 8) = o;
    }
}

// ---- main flash kernel: 4 waves x 64 q = 256 q per block.
// nhalf==1: 512 blocks, 32 K-tiles each (R12 behavior).
// nhalf==2: 1024 blocks, 16 K-tiles each, atomic combine.
__global__ __launch_bounds__(256, 2) void fa_kernel(
    const float* __restrict__ qg, const _Float16* __restrict__ kh,
    const _Float16* __restrict__ vt, float* __restrict__ outg,
    float* __restrict__ op, float* __restrict__ lacp,
    int* __restrict__ flags, int nhalf)
{
    // Static double buffers. [row][phys 16B chunk], phys = logical ^ (row&7).
    __shared__ _Float16 Kl0[64 * 64];   // [key][d]
    __shared__ _Float16 Kl1[64 * 64];
    __shared__ _Float16 Vl0[64 * 64];   // [d][pos]  (pos = permuted key)
    __shared__ _Float16 Vl1[64 * 64];
    __shared__ int role;

    const int tid = threadIdx.x;
    const int w = tid >> 6;            // wave 0..3
    const int L = tid & 63;
    const int lq = L & 31;
    const int h = L >> 5;

    // id = [kvh(1b)][qblk(3b)][bh_lo(3b)][xcd(3b)]; partner differs in bit9
    // only -> same XCD under %8 round-robin (L2-local partial exchange).
    const int id = blockIdx.x;
    const int bh   = ((id & 7) << 3) | ((id >> 3) & 7);
    const int qblk = (id >> 6) & 7;    // 8 q-blocks of 256 q
    const int kvh  = (id >> 9) & 1;    // key-half; 0 when grid=512
    const int qrowA = qblk * 256 + w * 32 + lq;
    const int kbase = kvh * (S_LEN / 2);   // first key of this block's range

    // Q fragments (B operand of S^T): B[k=d][n=q], k = 16*ks + 8*h + j
    half8 qbA[4], qbB[4];
    {
        const float* qpA = qg + ((size_t)bh * S_LEN + qrowA) * D_DIM + h * 8;
        const float* qpB = qpA + 128 * D_DIM;
#pragma unroll
        for (int ks = 0; ks < 4; ++ks) {
            const float4 a0 = *(const float4*)(qpA + ks * 16);
            const float4 b0 = *(const float4*)(qpA + ks * 16 + 4);
            const float4 a1 = *(const float4*)(qpB + ks * 16);
            const float4 b1 = *(const float4*)(qpB + ks * 16 + 4);
            qbA[ks][0] = (_Float16)(a0.x * QSCALE);
            qbA[ks][1] = (_Float16)(a0.y * QSCALE);
            qbA[ks][2] = (_Float16)(a0.z * QSCALE);
            qbA[ks][3] = (_Float16)(a0.w * QSCALE);
            qbA[ks][4] = (_Float16)(b0.x * QSCALE);
            qbA[ks][5] = (_Float16)(b0.y * QSCALE);
            qbA[ks][6] = (_Float16)(b0.z * QSCALE);
            qbA[ks][7] = (_Float16)(b0.w * QSCALE);
            qbB[ks][0] = (_Float16)(a1.x * QSCALE);
            qbB[ks][1] = (_Float16)(a1.y * QSCALE);
            qbB[ks][2] = (_Float16)(a1.z * QSCALE);
            qbB[ks][3] = (_Float16)(a1.w * QSCALE);
            qbB[ks][4] = (_Float16)(b1.x * QSCALE);
            qbB[ks][5] = (_Float16)(b1.y * QSCALE);
            qbB[ks][6] = (_Float16)(b1.z * QSCALE);
            qbB[ks][7] = (_Float16)(b1.w * QSCALE);
        }
    }

    floatx16 o0A, o1A, lacA, o0B, o1B, lacB;
#pragma unroll
    for (int r = 0; r < 16; ++r) {
        o0A[r] = 0.f; o1A[r] = 0.f; lacA[r] = 0.f;
        o0B[r] = 0.f; o1B[r] = 0.f; lacB[r] = 0.f;
    }

    half8 ones;
#pragma unroll
    for (int j = 0; j < 8; ++j) ones[j] = (_Float16)1.0f;

    // staging: wave w covers rows [w*16, w*16+16), 2 GLL16 each for K and V.
    const int rloc = L >> 3, lc = L & 7;
    const int crd = lc ^ rloc;
    const _Float16* kgl = kh + (size_t)bh * S_LEN * D_DIM
                        + (size_t)(kbase + w * 16 + rloc) * D_DIM + crd * 8;
    const _Float16* vgl = vt + (size_t)bh * D_DIM * S_LEN
                        + (size_t)(w * 16 + rloc) * S_LEN + kbase + crd * 8;
    const int woff = w * 16 * 64;

#define STAGE(KD, VD) do {                                                 \
        GLL16(kgl,                     &KD[woff]);                         \
        GLL16(kgl + (size_t)8 * D_DIM, &KD[woff + 8 * 64]);                \
        GLL16(vgl,                     &VD[woff]);                         \
        GLL16(vgl + (size_t)8 * S_LEN, &VD[woff + 8 * 64]);                \
        kgl += 64 * D_DIM;                                                 \
        vgl += 64;                                                         \
    } while (0)

#define COMPUTE(KB, VB) do {                                               \
        /* S^T = K Q^T for both q-groups; K fragments read ONCE */         \
        floatx16 s0A, s1A, s0B, s1B;                                       \
        _Pragma("unroll")                                                  \
        for (int r = 0; r < 16; ++r) {                                     \
            s0A[r] = 0.f; s1A[r] = 0.f; s0B[r] = 0.f; s1B[r] = 0.f;        \
        }                                                                  \
        __builtin_amdgcn_s_setprio(1);                                     \
        _Pragma("unroll")                                                  \
        for (int ks = 0; ks < 4; ++ks) {                                   \
            const int sw = (((2 * ks + h) ^ (lq & 7)) << 3);               \
            const half8 ka0 = *(const half8*)&KB[lq * 64 + sw];            \
            const half8 ka1 = *(const half8*)&KB[(32 + lq) * 64 + sw];     \
            s0A = MFMA32(ka0, qbA[ks], s0A);                               \
            s1A = MFMA32(ka1, qbA[ks], s1A);                               \
            s0B = MFMA32(ka0, qbB[ks], s0B);                               \
            s1B = MFMA32(ka1, qbB[ks], s1B);                               \
        }                                                                  \
        __builtin_amdgcn_s_setprio(0);                                     \
        /* P = exp2(S^T); pk regs ARE the A-fragments */                   \
        unsigned int pkA0[8], pkA1[8], pkB0[8], pkB1[8];                   \
        _Pragma("unroll")                                                  \
        for (int p = 0; p < 8; ++p) {                                      \
            const auto eA0 = __builtin_amdgcn_cvt_pkrtz(                   \
                __builtin_amdgcn_exp2f(s0A[2 * p]),                        \
                __builtin_amdgcn_exp2f(s0A[2 * p + 1]));                   \
            const auto eA1 = __builtin_amdgcn_cvt_pkrtz(                   \
                __builtin_amdgcn_exp2f(s1A[2 * p]),                        \
                __builtin_amdgcn_exp2f(s1A[2 * p + 1]));                   \
            pkA0[p] = __builtin_bit_cast(unsigned int, eA0);               \
            pkA1[p] = __builtin_bit_cast(unsigned int, eA1);               \
        }                                                                  \
        _Pragma("unroll")                                                  \
        for (int p = 0; p < 8; ++p) {                                      \
            const auto eB0 = __builtin_amdgcn_cvt_pkrtz(                   \
                __builtin_amdgcn_exp2f(s0B[2 * p]),                        \
                __builtin_amdgcn_exp2f(s0B[2 * p + 1]));                   \
            const auto eB1 = __builtin_amdgcn_cvt_pkrtz(                   \
                __builtin_amdgcn_exp2f(s1B[2 * p]),                        \
                __builtin_amdgcn_exp2f(s1B[2 * p + 1]));                   \
            pkB0[p] = __builtin_bit_cast(unsigned int, eB0);               \
            pkB1[p] = __builtin_bit_cast(unsigned int, eB1);               \
        }                                                                  \
        /* O += P V ; lac += (af0+af1) * ones; V fragments read ONCE */    \
        __builtin_amdgcn_s_setprio(1);                                     \
        _Pragma("unroll")                                                  \
        for (int mt = 0; mt < 2; ++mt) {                                   \
            const unsigned int* pA = mt ? pkA1 : pkA0;                     \
            const unsigned int* pB = mt ? pkB1 : pkB0;                     \
            const uint4v uA0 = {pA[0], pA[1], pA[2], pA[3]};               \
            const uint4v uA1 = {pA[4], pA[5], pA[6], pA[7]};               \
            const uint4v uB0 = {pB[0], pB[1], pB[2], pB[3]};               \
            const uint4v uB1 = {pB[4], pB[5], pB[6], pB[7]};               \
            const half8 afA0 = __builtin_bit_cast(half8, uA0);             \
            const half8 afA1 = __builtin_bit_cast(half8, uA1);             \
            const half8 afB0 = __builtin_bit_cast(half8, uB0);             \
            const half8 afB1 = __builtin_bit_cast(half8, uB1);             \
            lacA = MFMA32(afA0 + afA1, ones, lacA);                        \
            lacB = MFMA32(afB0 + afB1, ones, lacB);                        \
            _Pragma("unroll")                                              \
            for (int kl = 0; kl < 2; ++kl) {                               \
                const int ksg = mt * 2 + kl;                               \
                const int sw = (((2 * ksg + h) ^ (lq & 7)) << 3);          \
                const half8 vb0 = *(const half8*)&VB[lq * 64 + sw];        \
                const half8 vb1 = *(const half8*)&VB[(32 + lq) * 64 + sw]; \
                const half8 afA = kl ? afA1 : afA0;                        \
                const half8 afB = kl ? afB1 : afB0;                        \
                o0A = MFMA32(afA, vb0, o0A);                               \
                o1A = MFMA32(afA, vb1, o1A);                               \
                o0B = MFMA32(afB, vb0, o0B);                               \
                o1B = MFMA32(afB, vb1, o1B);                               \
            }                                                              \
        }                                                                  \
        __builtin_amdgcn_s_setprio(0);                                     \
    } while (0)

    // ---- prologue: stage tile 0 into buffer 0, drain ----
    STAGE(Kl0, Vl0);
    __syncthreads();   // tile 0 staged (implicit vmcnt(0) before s_barrier)

    // ---- main loop: 2 tiles/iter, static ping-pong, 1 barrier/tile ----
    const int niter = (nhalf == 2) ? 7 : 15;   // (ntiles/2 - 1)
    for (int it = 0; it < niter; ++it) {
        STAGE(Kl1, Vl1);
        COMPUTE(Kl0, Vl0);
        __syncthreads();
        STAGE(Kl0, Vl0);
        COMPUTE(Kl1, Vl1);
        __syncthreads();
    }
    STAGE(Kl1, Vl1);            // last tile
    COMPUTE(Kl0, Vl0);
    __syncthreads();
    COMPUTE(Kl1, Vl1);          // last tile (no prefetch)

#undef STAGE
#undef COMPUTE

    const size_t qoff = (size_t)bh * S_LEN + qblk * 256 + w * 32;

    if (nhalf == 1) {
        // ---- single-pass epilogue (R12) ----
        float* obA = outg + qoff * D_DIM;
        float* obB = obA + (size_t)128 * D_DIM;
#pragma unroll
        for (int reg = 0; reg < 16; ++reg) {
            const int q = (reg & 3) + 8 * (reg >> 2) + 4 * h;
            const float invA = 1.0f / lacA[reg];
            const float invB = 1.0f / lacB[reg];
            obA[(size_t)q * D_DIM + lq]      = o0A[reg] * invA;
            obA[(size_t)q * D_DIM + 32 + lq] = o1A[reg] * invA;
            obB[(size_t)q * D_DIM + lq]      = o0B[reg] * invB;
            obB[(size_t)q * D_DIM + 32 + lq] = o1B[reg] * invB;
        }
        return;
    }

    // ---- split-K epilogue: store partials, fence, race, loser combines ----
    {
        const size_t HOP = (size_t)N_BH * S_LEN * D_DIM;   // floats per half
        const size_t HLC = (size_t)N_BH * S_LEN;
        float* pb = op + (size_t)kvh * HOP + qoff * D_DIM;
        float* pl = lacp + (size_t)kvh * HLC + qoff;
#pragma unroll
        for (int reg = 0; reg < 16; ++reg) {
            const int q = (reg & 3) + 8 * (reg >> 2) + 4 * h;
            pb[(size_t)q * D_DIM + lq]              = o0A[reg];
            pb[(size_t)q * D_DIM + 32 + lq]         = o1A[reg];
            pb[(size_t)(128 + q) * D_DIM + lq]      = o0B[reg];
            pb[(size_t)(128 + q) * D_DIM + 32 + lq] = o1B[reg];
            if (lq == 0) { pl[q] = lacA[reg]; pl[128 + q] = lacB[reg]; }
        }
        __threadfence();                 // EVERY thread: own partials device-visible
        __syncthreads();                 // all fences complete
        if (tid == 0) role = atomicAdd(&flags[(bh << 3) | qblk], 1);
        __syncthreads();
        if (role == 1) {                 // partner's partials fenced before its add
            const float* qb_ = op + (size_t)(kvh ^ 1) * HOP + qoff * D_DIM;
            const float* ql_ = lacp + (size_t)(kvh ^ 1) * HLC + qoff;
            float* ob = outg + qoff * D_DIM;
#pragma unroll
            for (int reg = 0; reg < 16; ++reg) {
                const int q = (reg & 3) + 8 * (reg >> 2) + 4 * h;
                const float invA = 1.0f / (lacA[reg] + ql_[q]);
                const float invB = 1.0f / (lacB[reg] + ql_[128 + q]);
                ob[(size_t)q * D_DIM + lq] =
                    (o0A[reg] + qb_[(size_t)q * D_DIM + lq]) * invA;
                ob[(size_t)q * D_DIM + 32 + lq] =
                    (o1A[reg] + qb_[(size_t)q * D_DIM + 32 + lq]) * invA;
                ob[(size_t)(128 + q) * D_DIM + lq] =
                    (o0B[reg] + qb_[(size_t)(128 + q) * D_DIM + lq]) * invB;
                ob[(size_t)(128 + q) * D_DIM + 32 + lq] =
                    (o1B[reg] + qb_[(size_t)(128 + q) * D_DIM + 32 + lq]) * invB;
            }
        }
    }
}

extern "C" void kernel_launch(void* const* d_in, const int* in_sizes, int n_in,
                              void* d_out, int out_size, void* d_ws, size_t ws_size,
                              hipStream_t stream) {
    const float* q = (const float*)d_in[0];
    const float* k = (const float*)d_in[1];
    const float* v = (const float*)d_in[2];
    float* out = (float*)d_out;
    (void)in_sizes; (void)n_in; (void)out_size;

    const size_t KH = (size_t)N_BH * S_LEN * D_DIM * 2;       // 16.78 MB
    const size_t OP = (size_t)2 * N_BH * S_LEN * D_DIM * 4;   // 67.11 MB
    const size_t LC = (size_t)2 * N_BH * S_LEN * 4;           // 1.05 MB
    const size_t need = 2 * KH + OP + LC + 2048;              // 101.7 MB

    _Float16* kh = (_Float16*)d_ws;
    _Float16* vt = (_Float16*)((char*)d_ws + KH);
    float* op    = (float*)((char*)d_ws + 2 * KH);
    float* lacp  = (float*)((char*)d_ws + 2 * KH + OP);
    int*   flags = (int*)((char*)d_ws + 2 * KH + OP + LC);

    const int nhalf = (ws_size >= need) ? 2 : 1;

    prep_kernel<<<dim3(S_LEN / 128, N_BH), dim3(256), 0, stream>>>(
        k, v, kh, vt, flags, nhalf);
    fa_kernel<<<dim3(512 * nhalf), dim3(256), 0, stream>>>(
        q, kh, vt, out, op, lacp, flags, nhalf);
}